// Round 3
// baseline (312.641 us; speedup 1.0000x reference)
//
#include <hip/hip_runtime.h>

typedef unsigned short u16;

#define M_ROWS 8192
#define N_ROWS 16384
#define KDIM   512
#define BM     256
#define BN     128
#define BK     32
#define NCHUNKS 16
#define NPER   (N_ROWS / NCHUNKS)   /* 1024 */
#define TOPK   9

#define ASZ (BM * BK)               /* 8192 u16 = 16 KB per A buffer */
#define BSZ (BN * BK)               /* 4096 u16 =  8 KB per B buffer */
#define NTT ((NPER / BN) * (KDIM / BK))   /* 8 nt * 16 kc = 128 tiles */

typedef __attribute__((ext_vector_type(8)))  short bf16x8;
typedef __attribute__((ext_vector_type(16))) float f32x16;

__device__ __forceinline__ void gload_lds16(const void* g, void* l) {
  __builtin_amdgcn_global_load_lds(
      (const __attribute__((address_space(1))) void*)g,
      (__attribute__((address_space(3))) void*)l,
      16, 0, 0);
}

__device__ __forceinline__ u16 f2bf(float x) {
  union { float f; unsigned u; } c; c.f = x;
  unsigned u = c.u;
  u += 0x7fffu + ((u >> 16) & 1u);   // RNE; inputs finite randn
  return (u16)(u >> 16);
}

__device__ __forceinline__ void topk_update(float v, float* best) {
  if (v < best[TOPK - 1]) {
    #pragma unroll
    for (int i = 0; i < TOPK; ++i) {
      float b = best[i];
      best[i] = fminf(b, v);
      v = fmaxf(b, v);
    }
  }
}

// ---- Kernel 1: fp32 -> bf16 convert + fp32 row norms; mb norms scattered into
//      MFMA-C-layout permuted order so the GEMM epilogue reads them as broadcasts.
__global__ __launch_bounds__(256) void prep_kernel(
    const float* __restrict__ fv, const float* __restrict__ mb,
    u16* __restrict__ fvb, u16* __restrict__ mbb,
    float* __restrict__ nf, float* __restrict__ nm_perm)
{
  int idx = blockIdx.x * 4 + (threadIdx.x >> 6);   // one wave per row
  int l = threadIdx.x & 63;
  const float* src; u16* dst;
  if (idx < M_ROWS) {
    src = fv + (size_t)idx * KDIM; dst = fvb + (size_t)idx * KDIM;
  } else {
    int r = idx - M_ROWS;
    src = mb + (size_t)r * KDIM; dst = mbb + (size_t)r * KDIM;
  }
  float4 x0 = ((const float4*)src)[2 * l];
  float4 x1 = ((const float4*)src)[2 * l + 1];
  float s = x0.x * x0.x + x0.y * x0.y + x0.z * x0.z + x0.w * x0.w
          + x1.x * x1.x + x1.y * x1.y + x1.z * x1.z + x1.w * x1.w;
  uint4 o;
  o.x = (unsigned)f2bf(x0.x) | ((unsigned)f2bf(x0.y) << 16);
  o.y = (unsigned)f2bf(x0.z) | ((unsigned)f2bf(x0.w) << 16);
  o.z = (unsigned)f2bf(x1.x) | ((unsigned)f2bf(x1.y) << 16);
  o.w = (unsigned)f2bf(x1.z) | ((unsigned)f2bf(x1.w) << 16);
  ((uint4*)dst)[l] = o;
  #pragma unroll
  for (int off = 32; off > 0; off >>= 1) s += __shfl_down(s, off, 64);
  if (l == 0) {
    if (idx < M_ROWS) {
      nf[idx] = s;
    } else {
      // 32x32 C/D: within-tile row w5 = (r&3) + 8*(r>>2) + 4*h  ->  [tile][h][r]
      int n  = idx - M_ROWS;
      int ig = n >> 5;            // global 32-row tile index (512 tiles)
      int w5 = n & 31;
      int h  = (w5 >> 2) & 1;
      int r  = (w5 & 3) | ((w5 >> 3) << 2);
      nm_perm[(ig * 2 + h) * 16 + r] = s;
    }
  }
}

// ---- Kernel 2: bf16 32x32x16 MFMA GEMM (swapped operands) + per-thread top-9 ----
// grid (32, 16), block 256 (4 waves). Block: 256 fv-rows (m) x 1024 mb-rows (n).
// R3 change (T3/T4): BK=32, 3-buffer LDS ring (72 KB dyn, 2 blocks/CU). Flattened
// tile loop tt = nt*16 + kc; stage tile tt+2 BEFORE computing tt; end-of-tile wait
// is counted vmcnt(6) (only tt+2's 6 loads may stay in flight) -> load latency is
// hidden under ~2 tiles of compute instead of exposed per-kc (R2: stage->drain(0)
// ->compute was stall-bound: MfmaUtil 27 / LDS 28 / VALU 46, nothing saturated).
// One raw s_barrier per tile (was 2 __syncthreads + implicit full drain).
// Swizzle (BK=32): LDS chunk c of row r holds global chunk c^((r>>1)&3); staging
// pre-swizzles the per-lane SOURCE k-offset, frag reads XOR the chunk. Spreads a
// 32-row column read over all 8 bank-quads (verified on paper: quads {0,4,1,5,
// 2,6,3,7} for r=0..7) -> ~0 conflicts.
__global__ __launch_bounds__(256, 2) void gemm_topk_kernel(
    const u16* __restrict__ fvb, const u16* __restrict__ mbb,
    const float* __restrict__ nm_perm, float* __restrict__ partial)
{
  extern __shared__ __align__(16) u16 sm[];
  u16* const Asm = sm;                 // 3 x [256][32] fv tiles, 48 KB
  u16* const Bsm = sm + 3 * ASZ;       // 3 x [128][32] mb tiles, 24 KB

  const int t   = threadIdx.x;
  const int l   = t & 63;
  const int w   = t >> 6;
  const int h   = l >> 5;        // half-wave: k-slice half
  const int c31 = l & 31;
  const int xr  = (c31 >> 1) & 3;      // read-side row swizzle bits

  const int m0    = blockIdx.x * BM;
  const int ncoff = blockIdx.y * NPER;

  // staging: lane l covers row (base + l>>2), chunk l&3; source chunk pre-swizzled
  const int srow = l >> 2;                       // 0..15
  const int sc   = ((l & 3) ^ ((l >> 3) & 3)) * 8;   // swizzled source k-off (u16)

  const u16* aSrc = fvb + (size_t)(m0 + w * 64 + srow) * KDIM + sc;
  const u16* bSrc = mbb + (size_t)(ncoff + w * 32 + srow) * KDIM + sc;

  // LDS frag-read offsets (u16 units)
  const int aRd  = (w * 64 + c31) * BK;
  const int ch0  = (h ^ xr) * 8;        // kk=0 chunk
  const int ch1  = ch0 ^ 16;            // kk=1 chunk ( (2+h)^xr = (h^xr)^2 )

#define STAGE(kc2_, bufS_) do {                                               \
    const size_t ao_ = (size_t)((kc2_) & 15) * BK;                            \
    const size_t so_ = (size_t)((kc2_) >> 4) * ((size_t)BN * KDIM) + ao_;     \
    u16* ad_ = Asm + (bufS_) * ASZ + (w * 64) * BK;                           \
    u16* bd_ = Bsm + (bufS_) * BSZ + (w * 32) * BK;                           \
    gload_lds16(aSrc + ao_,                 ad_);                             \
    gload_lds16(aSrc + ao_ + 16 * KDIM,     ad_ + 16 * BK);                   \
    gload_lds16(aSrc + ao_ + 32 * KDIM,     ad_ + 32 * BK);                   \
    gload_lds16(aSrc + ao_ + 48 * KDIM,     ad_ + 48 * BK);                   \
    gload_lds16(bSrc + so_,                 bd_);                             \
    gload_lds16(bSrc + so_ + 16 * KDIM,     bd_ + 16 * BK);                   \
  } while (0)

  float best[2][TOPK];
  float T[2];
  #pragma unroll
  for (int s = 0; s < 2; ++s) {
    T[s] = 3.4e38f;
    #pragma unroll
    for (int i = 0; i < TOPK; ++i) best[s][i] = 3.4e38f;
  }

  f32x16 acc[2][4];

  // prologue: prime ring with tiles 0,1 (12 loads in flight), tile 0 resident
  STAGE(0, 0);
  STAGE(1, 1);
  asm volatile("s_waitcnt vmcnt(6)" ::: "memory");
  __builtin_amdgcn_s_barrier();

  int bC = 0, bS = 2;
  for (int tt = 0; tt < NTT; ++tt) {
    if ((tt & 15) == 0) {
      #pragma unroll
      for (int s = 0; s < 2; ++s)
        #pragma unroll
        for (int i = 0; i < 4; ++i)
          #pragma unroll
          for (int r = 0; r < 16; ++r) acc[s][i][r] = 0.0f;
    }

    const int kc2 = tt + 2;
    if (kc2 < NTT) STAGE(kc2, bS);

    // ---- compute tile tt from buffer bC ----
    {
      const u16* Ak = Asm + bC * ASZ;
      const u16* Bk = Bsm + bC * BSZ;
      {
        bf16x8 f0 = *(const bf16x8*)&Ak[aRd + ch0];
        bf16x8 f1 = *(const bf16x8*)&Ak[aRd + 32 * BK + ch0];
        #pragma unroll
        for (int i = 0; i < 4; ++i) {
          bf16x8 mbf = *(const bf16x8*)&Bk[(i * 32 + c31) * BK + ch0];
          acc[0][i] = __builtin_amdgcn_mfma_f32_32x32x16_bf16(mbf, f0, acc[0][i], 0, 0, 0);
          acc[1][i] = __builtin_amdgcn_mfma_f32_32x32x16_bf16(mbf, f1, acc[1][i], 0, 0, 0);
        }
      }
      {
        bf16x8 f0 = *(const bf16x8*)&Ak[aRd + ch1];
        bf16x8 f1 = *(const bf16x8*)&Ak[aRd + 32 * BK + ch1];
        #pragma unroll
        for (int i = 0; i < 4; ++i) {
          bf16x8 mbf = *(const bf16x8*)&Bk[(i * 32 + c31) * BK + ch1];
          acc[0][i] = __builtin_amdgcn_mfma_f32_32x32x16_bf16(mbf, f0, acc[0][i], 0, 0, 0);
          acc[1][i] = __builtin_amdgcn_mfma_f32_32x32x16_bf16(mbf, f1, acc[1][i], 0, 0, 0);
        }
      }
    }

    // ---- counted end-of-tile wait: tile tt+1 resident after this barrier ----
    if (tt < NTT - 1) {
      if (tt < NTT - 2) { asm volatile("s_waitcnt vmcnt(6)" ::: "memory"); }
      else              { asm volatile("s_waitcnt vmcnt(0)" ::: "memory"); }
      __builtin_amdgcn_s_barrier();
    }

    // ---- per-n-tile register epilogue (after barrier; regs + global only) ----
    if ((tt & 15) == 15) {
      const int nt    = tt >> 4;
      const int nbase = ncoff + nt * BN;
      #pragma unroll
      for (int i = 0; i < 4; ++i) {
        const float4* np = (const float4*)&nm_perm[(((nbase >> 5) + i) * 2 + h) * 16];
        float4 q0 = np[0], q1 = np[1], q2 = np[2], q3 = np[3];
        #pragma unroll
        for (int s = 0; s < 2; ++s) {
          float v[16];
          v[ 0] = fmaf(-2.0f, acc[s][i][ 0], q0.x);
          v[ 1] = fmaf(-2.0f, acc[s][i][ 1], q0.y);
          v[ 2] = fmaf(-2.0f, acc[s][i][ 2], q0.z);
          v[ 3] = fmaf(-2.0f, acc[s][i][ 3], q0.w);
          v[ 4] = fmaf(-2.0f, acc[s][i][ 4], q1.x);
          v[ 5] = fmaf(-2.0f, acc[s][i][ 5], q1.y);
          v[ 6] = fmaf(-2.0f, acc[s][i][ 6], q1.z);
          v[ 7] = fmaf(-2.0f, acc[s][i][ 7], q1.w);
          v[ 8] = fmaf(-2.0f, acc[s][i][ 8], q2.x);
          v[ 9] = fmaf(-2.0f, acc[s][i][ 9], q2.y);
          v[10] = fmaf(-2.0f, acc[s][i][10], q2.z);
          v[11] = fmaf(-2.0f, acc[s][i][11], q2.w);
          v[12] = fmaf(-2.0f, acc[s][i][12], q3.x);
          v[13] = fmaf(-2.0f, acc[s][i][13], q3.y);
          v[14] = fmaf(-2.0f, acc[s][i][14], q3.z);
          v[15] = fmaf(-2.0f, acc[s][i][15], q3.w);
          float bmin = 3.4e38f;
          #pragma unroll
          for (int r = 0; r < 16; ++r) bmin = fminf(bmin, v[r]);
          if (bmin < T[s]) {
            #pragma unroll
            for (int r = 0; r < 16; ++r) topk_update(v[r], best[s]);
            T[s] = best[s][TOPK - 1];
          }
        }
      }
      #pragma unroll
      for (int s = 0; s < 2; ++s)
        T[s] = fminf(best[s][TOPK - 1], __shfl_xor(best[s][TOPK - 1], 32, 64));
    }

    bC = (bC == 2) ? 0 : bC + 1;
    bS = (bS == 2) ? 0 : bS + 1;
  }

  // merge the lane pair sharing each m-col (snapshot partner list, then insert)
  #pragma unroll
  for (int s = 0; s < 2; ++s) {
    float tmp[TOPK];
    #pragma unroll
    for (int q = 0; q < TOPK; ++q) tmp[q] = __shfl_xor(best[s][q], 32, 64);
    #pragma unroll
    for (int q = 0; q < TOPK; ++q) topk_update(tmp[q], best[s]);
    int m = m0 + w * 64 + s * 32 + c31;
    size_t base = ((size_t)blockIdx.y * M_ROWS + m) * TOPK;
    if (h == 0) {
      #pragma unroll
      for (int q = 0; q < 5; ++q) partial[base + q] = best[s][q];
    } else {
      #pragma unroll
      for (int q = 5; q < TOPK; ++q) partial[base + q] = best[s][q];
    }
  }
}

// ---------------- Kernel 3: merge 16 partial lists/row, sqrt, pixel scores ----------------
__global__ __launch_bounds__(256) void merge_kernel(
    const float* __restrict__ partial, const float* __restrict__ nf,
    float* __restrict__ final9, float* __restrict__ out_pix)
{
  int row = blockIdx.x * 256 + threadIdx.x;   // 8192 rows
  float best[TOPK];
  #pragma unroll
  for (int i = 0; i < TOPK; ++i) best[i] = 3.4e38f;
  for (int s = 0; s < NCHUNKS; ++s) {
    const float* p = &partial[((size_t)s * M_ROWS + row) * TOPK];
    #pragma unroll
    for (int i = 0; i < TOPK; ++i) topk_update(p[i], best);
  }
  float nfr = nf[row];
  float d[TOPK];
  #pragma unroll
  for (int i = 0; i < TOPK; ++i) d[i] = sqrtf(fmaxf(best[i] + nfr, 0.0f));
  out_pix[row] = d[0];
  #pragma unroll
  for (int i = 0; i < TOPK; ++i) final9[(size_t)row * TOPK + i] = d[i];
}

// ---------------- Kernel 4: per-image argmax (first-max) + softmax score ----------------
__global__ __launch_bounds__(256) void img_kernel(
    const float* __restrict__ out_pix, const float* __restrict__ final9,
    const int* __restrict__ bptr, float* __restrict__ out_img)
{
  int img = blockIdx.x, t = threadIdx.x;
  float bv = -1.0f; int bi = 0;
  for (int p = t; p < 1024; p += 256) {
    float v = out_pix[img * 1024 + p];
    if (v > bv) { bv = v; bi = p; }
  }
  __shared__ float sv[256];
  __shared__ int   si[256];
  sv[t] = bv; si[t] = bi;
  __syncthreads();
  for (int off = 128; off > 0; off >>= 1) {
    if (t < off) {
      float v2 = sv[t + off]; int i2 = si[t + off];
      if (v2 > sv[t] || (v2 == sv[t] && i2 < si[t])) { sv[t] = v2; si[t] = i2; }
    }
    __syncthreads();
  }
  if (t == 0) {
    int row = img * 1024 + si[0];
    int b = bptr[0];
    float s0 = final9[(size_t)row * TOPK + 0];
    float score = s0;
    if (b > 1) {
      int bb = b < TOPK ? b : TOPK;
      float mx = s0;
      for (int i = 1; i < bb; ++i) mx = fmaxf(mx, final9[(size_t)row * TOPK + i]);
      float den = 0.0f;
      for (int i = 0; i < bb; ++i) den += expf(final9[(size_t)row * TOPK + i] - mx);
      score = s0 * (1.0f - expf(s0 - mx) / den);
    }
    out_img[img] = score;
  }
}

extern "C" void kernel_launch(void* const* d_in, const int* in_sizes, int n_in,
                              void* d_out, int out_size, void* d_ws, size_t ws_size,
                              hipStream_t stream) {
  const float* fv   = (const float*)d_in[0];
  const float* mb   = (const float*)d_in[1];
  const int*   bptr = (const int*)d_in[2];
  float* out = (float*)d_out;

  char* ws = (char*)d_ws;
  u16*   fvb     = (u16*)ws;                       // 8388608 B
  u16*   mbb     = (u16*)(ws + 8388608);           // 16777216 B
  float* nf      = (float*)(ws + 25165824);        // 32768 B
  float* nm_perm = (float*)(ws + 25198592);        // 65536 B
  float* partial = (float*)(ws + 25264128);        // 16*8192*9*4 = 4718592 B
  float* final9  = (float*)(ws + 29982720);        // 294912 B   (end ~30.3 MB)

  hipLaunchKernelGGL(prep_kernel, dim3((M_ROWS + N_ROWS) / 4), dim3(256), 0, stream,
                     fv, mb, fvb, mbb, nf, nm_perm);
  hipLaunchKernelGGL(gemm_topk_kernel, dim3(M_ROWS / BM, NCHUNKS), dim3(256),
                     73728, stream, fvb, mbb, nm_perm, partial);
  hipLaunchKernelGGL(merge_kernel, dim3(M_ROWS / 256), dim3(256), 0, stream,
                     partial, nf, final9, out);
  hipLaunchKernelGGL(img_kernel, dim3(8), dim3(256), 0, stream,
                     out, final9, bptr, out + M_ROWS);
}